// Round 1
// baseline (116.200 us; speedup 1.0000x reference)
//
#include <hip/hip_runtime.h>

// Row-wise top-K(32) of relu(A), zero elsewhere. N=8192 fp32 per row.
// One block per row. Radix-select via 4096-bin histogram of float bits
// (bits>>19: sign|exp|5 mantissa bits — monotonic for positive floats).
// Exact tie-break (value desc, col asc) handled on the cutoff bin only.

constexpr int N     = 8192;
constexpr int K     = 32;
constexpr int NBINS = 4096;
constexpr int CAP   = 512;   // max candidates in cutoff bin (expected ~12, Poisson)
constexpr int BLOCK = 256;

__global__ __launch_bounds__(BLOCK)
void topk_relu_kernel(const float* __restrict__ A, float* __restrict__ Out) {
    const int row  = blockIdx.x;
    const int tid  = threadIdx.x;
    const int lane = tid & 63;
    const int wave = tid >> 6;

    __shared__ unsigned int hist[NBINS];
    __shared__ float        cand_val[CAP];
    __shared__ int          cand_col[CAP];
    __shared__ unsigned int cand_cnt;
    __shared__ int          sB, sG;

    #pragma unroll
    for (int i = 0; i < NBINS / BLOCK; ++i) hist[tid + i * BLOCK] = 0u;
    if (tid == 0) cand_cnt = 0u;
    __syncthreads();

    const float4* __restrict__ Arow = reinterpret_cast<const float4*>(A + (size_t)row * N);

    // ---- pass 1: load row to registers (coalesced), histogram positives ----
    float4 vf[8];
    #pragma unroll
    for (int i = 0; i < 8; ++i) vf[i] = Arow[i * BLOCK + tid];

    #pragma unroll
    for (int i = 0; i < 8; ++i) {
        { float f = vf[i].x; if (f > 0.0f) atomicAdd(&hist[__float_as_uint(f) >> 19], 1u); }
        { float f = vf[i].y; if (f > 0.0f) atomicAdd(&hist[__float_as_uint(f) >> 19], 1u); }
        { float f = vf[i].z; if (f > 0.0f) atomicAdd(&hist[__float_as_uint(f) >> 19], 1u); }
        { float f = vf[i].w; if (f > 0.0f) atomicAdd(&hist[__float_as_uint(f) >> 19], 1u); }
    }
    __syncthreads();

    // ---- pass 2: wave 0 finds cutoff bin B and G = count strictly above B ----
    if (wave == 0) {
        // group sums: lane l owns bins [l*64, l*64+64). Staggered read order
        // breaks the otherwise 64-way bank conflict (all lanes bank i%32).
        unsigned int s = 0;
        #pragma unroll
        for (int i = 0; i < 64; ++i) s += hist[lane * 64 + ((i + lane) & 63)];

        // inclusive suffix sum over lanes: acc[l] = sum_{j>=l} s[j]
        unsigned int acc = s;
        #pragma unroll
        for (int off = 1; off < 64; off <<= 1) {
            unsigned int t = __shfl_down(acc, off, 64);
            if (lane + off < 64) acc += t;
        }
        unsigned long long m = __ballot(acc >= (unsigned)K);
        if (m == 0ull) {
            // fewer than K positives in the row: keep every positive
            if (lane == 0) { sB = -1; sG = 0; }
        } else {
            int g = 63 - __clzll((long long)m);   // highest lane with suffix >= K
            unsigned int above = (g < 63) ? (unsigned)__shfl((int)acc, g + 1, 64) : 0u;
            // refine within group g (64 bins, one per lane; consecutive -> conflict-free)
            unsigned int h  = hist[g * 64 + lane];
            unsigned int a2 = h;
            #pragma unroll
            for (int off = 1; off < 64; off <<= 1) {
                unsigned int t = __shfl_down(a2, off, 64);
                if (lane + off < 64) a2 += t;
            }
            unsigned long long m2 = __ballot(above + a2 >= (unsigned)K);
            int bl = 63 - __clzll((long long)m2);
            unsigned int S2b = (unsigned)__shfl((int)a2, bl, 64) + above;
            unsigned int hb  = (unsigned)__shfl((int)h,  bl, 64);
            if (lane == 0) { sB = g * 64 + bl; sG = (int)(S2b - hb); }
        }
    }
    __syncthreads();

    const int B = sB;
    const int G = sG;

    // ---- pass 3: write output from registers; gather cutoff-bin candidates ----
    float* __restrict__ Orow = Out + (size_t)row * N;
    #pragma unroll
    for (int i = 0; i < 8; ++i) {
        float4 w;
        const int colbase = (i * BLOCK + tid) * 4;
        #define PROC(FF, CC, WW) { float f = (FF); float o = 0.0f;               \
            if (f > 0.0f) { int b = (int)(__float_as_uint(f) >> 19);             \
                if (b > B) o = f;                                                \
                else if (b == B) { unsigned ix = atomicAdd(&cand_cnt, 1u);       \
                    if (ix < CAP) { cand_val[ix] = f; cand_col[ix] = (CC); } } } \
            (WW) = o; }
        PROC(vf[i].x, colbase + 0, w.x)
        PROC(vf[i].y, colbase + 1, w.y)
        PROC(vf[i].z, colbase + 2, w.z)
        PROC(vf[i].w, colbase + 3, w.w)
        #undef PROC
        reinterpret_cast<float4*>(Orow)[i * BLOCK + tid] = w;
    }
    __syncthreads();   // drains vmem: pass-3 zero-writes complete before patches

    // ---- pass 4: wave 0 selects top-R of cutoff bin, (val desc, col asc) ----
    const int R = K - G;
    if (wave == 0 && B >= 0 && R > 0) {
        const int C = (int)min(cand_cnt, (unsigned)CAP);
        float v[8]; int c[8];
        #pragma unroll
        for (int s = 0; s < 8; ++s) {
            const int j = lane + s * 64;
            if (j < C) { v[s] = cand_val[j]; c[s] = cand_col[j]; }
            else       { v[s] = -1.0f;       c[s] = 0x7FFFFFFF; }
        }
        for (int r = 0; r < R; ++r) {
            // lane-local argmax over 8 static slots
            float bv = v[0]; int bc = c[0]; int bs = 0;
            #pragma unroll
            for (int s = 1; s < 8; ++s)
                if (v[s] > bv || (v[s] == bv && c[s] < bc)) { bv = v[s]; bc = c[s]; bs = s; }
            int bmeta = (bs << 6) | lane;
            // wave argmax butterfly (ties: smaller col wins; cols are unique)
            #pragma unroll
            for (int off = 32; off >= 1; off >>= 1) {
                float ov = __shfl_xor(bv, off, 64);
                int   oc = __shfl_xor(bc, off, 64);
                int   om = __shfl_xor(bmeta, off, 64);
                if (ov > bv || (ov == bv && oc < bc)) { bv = ov; bc = oc; bmeta = om; }
            }
            if (bv <= 0.0f) break;   // exhausted (unreachable: C >= R by construction)
            const int wl = bmeta & 63, ws = bmeta >> 6;
            if (lane == wl) {
                #pragma unroll
                for (int s = 0; s < 8; ++s) if (s == ws) v[s] = -1.0f;  // mark taken
            }
            if (lane == 0) Orow[bc] = bv;   // patch selected position
        }
    }
}

extern "C" void kernel_launch(void* const* d_in, const int* in_sizes, int n_in,
                              void* d_out, int out_size, void* d_ws, size_t ws_size,
                              hipStream_t stream) {
    const float* A   = (const float*)d_in[0];
    float*       Out = (float*)d_out;
    (void)in_sizes; (void)n_in; (void)d_ws; (void)ws_size; (void)out_size;
    topk_relu_kernel<<<dim3(N), dim3(BLOCK), 0, stream>>>(A, Out);
}